// Round 10
// baseline (389.473 us; speedup 1.0000x reference)
//
#include <hip/hip_runtime.h>
#include <hip/hip_bf16.h>
#include <cstddef>
#include <cstdint>

// Problem constants
#define B 4
#define T 2048
#define C 1024
#define NQ 8
#define D 128
#define M_ROWS (B * T)          // 8192
#define NTOT (2 * D + NQ * D)   // 1280: [k | v | q0..q7]

typedef __bf16 bf16x8 __attribute__((ext_vector_type(8)));
typedef float  f32x4  __attribute__((ext_vector_type(4)));

__device__ __forceinline__ ushort f2bf(float f) {
    union { float f; uint32_t u; } v; v.f = f;
    const uint32_t r = (v.u + 0x7fffu + ((v.u >> 16) & 1u)) >> 16;
    return (ushort)r;
}

__device__ __forceinline__ void gld_lds16(const ushort* g, ushort* lds_uniform) {
    __builtin_amdgcn_global_load_lds(
        (const __attribute__((address_space(1))) void*)g,
        (__attribute__((address_space(3))) void*)lds_uniform, 16, 0, 0);
}

// -------------------- x f32 -> bf16 --------------------
__global__ __launch_bounds__(256) void xcvt(const float* __restrict__ x,
                                            ushort* __restrict__ xb) {
    const size_t i = ((size_t)blockIdx.x * 256 + threadIdx.x) * 8;
    const float4 a = *(const float4*)(x + i);
    const float4 b = *(const float4*)(x + i + 4);
    uint4 o;
    o.x = f2bf(a.x) | ((uint32_t)f2bf(a.y) << 16);
    o.y = f2bf(a.z) | ((uint32_t)f2bf(a.w) << 16);
    o.z = f2bf(b.x) | ((uint32_t)f2bf(b.y) << 16);
    o.w = f2bf(b.z) | ((uint32_t)f2bf(b.w) << 16);
    *(uint4*)(xb + i) = o;
}

// -------------------- weight transpose+convert: src f32 [1024][NC] -> dst bf16 [NC][1024]
__device__ __forceinline__ void wtrans_body(const float* __restrict__ src,
                                            ushort* __restrict__ dst, int NC,
                                            int bx, int by) {
    __shared__ ushort Ts[64][72];
    const int tid = threadIdx.x;
    const int k0 = by * 64, c0 = bx * 64;
    {
        const int r = tid >> 2, cq = tid & 3;
#pragma unroll
        for (int i = 0; i < 4; ++i) {
            const int cc = cq * 16 + i * 4;
            const float4 v = *(const float4*)(src + (size_t)(k0 + r) * NC + c0 + cc);
            uint2 o;
            o.x = f2bf(v.x) | ((uint32_t)f2bf(v.y) << 16);
            o.y = f2bf(v.z) | ((uint32_t)f2bf(v.w) << 16);
            *(uint2*)(&Ts[r][cc]) = o;
        }
    }
    __syncthreads();
    {
        const int n = tid >> 2, kq = tid & 3;
        ushort vv[16];
#pragma unroll
        for (int j = 0; j < 16; ++j) vv[j] = Ts[kq * 16 + j][n];
        uint4 o0, o1;
        o0.x = vv[0] | ((uint32_t)vv[1] << 16);  o0.y = vv[2] | ((uint32_t)vv[3] << 16);
        o0.z = vv[4] | ((uint32_t)vv[5] << 16);  o0.w = vv[6] | ((uint32_t)vv[7] << 16);
        o1.x = vv[8] | ((uint32_t)vv[9] << 16);  o1.y = vv[10] | ((uint32_t)vv[11] << 16);
        o1.z = vv[12] | ((uint32_t)vv[13] << 16); o1.w = vv[14] | ((uint32_t)vv[15] << 16);
        ushort* d = dst + (size_t)(c0 + n) * C + k0 + kq * 16;
        *(uint4*)d = o0;
        *(uint4*)(d + 8) = o1;
    }
}

// merged weight transpose: flat grid of 576 blocks.
// ids 0..319: QKV weights (z = id/32: 0->Wk, 1->Wv, 2..9->Wq[h]; rem: bx=rem&1, by=rem>>1)
// ids 320..575: Wp (id2 = id-320: bx = id2&15, by = id2>>4)
__global__ __launch_bounds__(256) void wtrans_all(const float* __restrict__ Wk,
                                                  const float* __restrict__ Wv,
                                                  const float* __restrict__ Wq,
                                                  const float* __restrict__ Wp,
                                                  ushort* __restrict__ WcatT,
                                                  ushort* __restrict__ WpT) {
    const int id = blockIdx.x;
    if (id < 320) {
        const int z = id >> 5, rem = id & 31;
        const float* src;
        int rbase;
        if (z == 0)      { src = Wk; rbase = 0; }
        else if (z == 1) { src = Wv; rbase = D; }
        else             { src = Wq + (size_t)(z - 2) * C * D; rbase = 2 * D + (z - 2) * D; }
        wtrans_body(src, WcatT + (size_t)rbase * C, D, rem & 1, rem >> 1);
    } else {
        const int id2 = id - 320;
        wtrans_body(Wp, WpT, C, id2 & 15, id2 >> 4);
    }
}

// -------------------- v transpose with per-32-key interleave permutation -----
// vb rows are qkv[row][D..2D); out vbT[d][g*32 + pi(k)], pi(k) = (k&15)*2 + (k>>4)
__global__ __launch_bounds__(256) void vtrans(const ushort* __restrict__ qkv,
                                              ushort* __restrict__ vbT) {
    __shared__ ushort Ts[64][136];
    const int tid = threadIdx.x;
    const int kb0 = blockIdx.x * 64;
    {
        const int r = tid >> 2, cq = tid & 3;
        const ushort* src = qkv + (size_t)(kb0 + r) * NTOT + D;
#pragma unroll
        for (int i = 0; i < 4; ++i) {
            const int cc = (cq * 4 + i) * 8;
            *(uint4*)(&Ts[r][cc]) = *(const uint4*)(src + cc);
        }
    }
    __syncthreads();
    {
        const int d = tid >> 1, half = tid & 1;
        ushort vv[32];
#pragma unroll
        for (int k = 0; k < 32; ++k) vv[k] = Ts[half * 32 + k][d];
        uint32_t dw[16];
#pragma unroll
        for (int i = 0; i < 16; ++i) dw[i] = vv[i] | ((uint32_t)vv[16 + i] << 16);
        uint32_t* dst = (uint32_t*)(vbT + (size_t)d * M_ROWS + kb0 + half * 32);
#pragma unroll
        for (int i = 0; i < 4; ++i)
            *(uint4*)(dst + i * 4) = *(uint4*)(&dw[i * 4]);
    }
}

// -------------------- MFMA GEMM: A bf16 [M][1024] @ Bt bf16 [N][1024]^T -----
template <bool BF16_OUT>
__global__ __launch_bounds__(256) void gemm_mfma(const ushort* __restrict__ A,
                                                 const ushort* __restrict__ Bt,
                                                 void* __restrict__ Cout,
                                                 const float* __restrict__ bias,
                                                 const int Nout) {
    __shared__ ushort As[128 * 32];
    __shared__ ushort Bs[128 * 32];
    const int tid  = threadIdx.x;
    const int lane = tid & 63;
    const int w    = tid >> 6;
    const int col  = lane & 15;
    const int quad = lane >> 4;
    const int row0 = blockIdx.y * 128;
    const int col0 = blockIdx.x * 128;
    const int wm = w & 1, wn = w >> 1;

    const int srow = lane >> 2;
    const int skk  = (lane & 3) * 8;

    f32x4 acc[4][4];
#pragma unroll
    for (int i = 0; i < 4; ++i)
#pragma unroll
        for (int j = 0; j < 4; ++j) acc[i][j] = (f32x4){0.f, 0.f, 0.f, 0.f};

    for (int k0 = 0; k0 < C; k0 += 32) {
        __syncthreads();
#pragma unroll
        for (int j = 0; j < 2; ++j) {
            const int ci = w * 2 + j;
            const int r  = ci * 16 + srow;
            gld_lds16(A  + (size_t)(row0 + r) * C + k0 + skk, &As[ci * 512]);
            gld_lds16(Bt + (size_t)(col0 + r) * C + k0 + skk, &Bs[ci * 512]);
        }
        __syncthreads();

        bf16x8 af[4], bfr[4];
#pragma unroll
        for (int i = 0; i < 4; ++i)
            af[i] = *(const bf16x8*)&As[(wm * 64 + i * 16 + col) * 32 + quad * 8];
#pragma unroll
        for (int j = 0; j < 4; ++j)
            bfr[j] = *(const bf16x8*)&Bs[(wn * 64 + j * 16 + col) * 32 + quad * 8];
#pragma unroll
        for (int i = 0; i < 4; ++i)
#pragma unroll
            for (int j = 0; j < 4; ++j)
                acc[i][j] = __builtin_amdgcn_mfma_f32_16x16x32_bf16(af[i], bfr[j], acc[i][j], 0, 0, 0);
    }

#pragma unroll
    for (int i = 0; i < 4; ++i) {
#pragma unroll
        for (int r = 0; r < 4; ++r) {
            const int grow = row0 + wm * 64 + i * 16 + quad * 4 + r;
#pragma unroll
            for (int j = 0; j < 4; ++j) {
                const int gcol = col0 + wn * 64 + j * 16 + col;
                const float v = acc[i][j][r];
                if (BF16_OUT) {
                    ((ushort*)Cout)[(size_t)grow * Nout + gcol] = f2bf(v);
                } else {
                    ((float*)Cout)[(size_t)grow * Nout + gcol] = v + bias[gcol];
                }
            }
        }
    }
}

// -------------------- MFMA flash attention --------------------
// v6: R8 structure (64-q blocks, 4 waves, balanced parity swizzle) + VGPR
// prefetch pipeline: global->VGPR loads for tile it+1 issue BEFORE computing
// tile it, so their latency hides behind ~2000 cyc of MFMA/exp instead of
// being drained at a barrier right after issue (the R8 stall). ds_write_b128
// staging replicates the gld_lds lane->16B placement exactly.
__global__ __launch_bounds__(256) void attn_mfma(const ushort* __restrict__ qkv,
                                                 const ushort* __restrict__ vbT,
                                                 ushort* __restrict__ attb) {
    __shared__ ushort Ks4[4][64][32];    // [d-chunk][key][32 d]  16 KB
    __shared__ ushort Vt4[4][128][16];   // [key-chunk][d][16 keys] 16 KB
    __shared__ ushort Pt[4][2][16][32];  // [wave][key-group][q-row][32 pkeys] 8 KB

    const int tid  = threadIdx.x;
    const int lane = tid & 63;
    const int w    = tid >> 6;
    const int col  = lane & 15;
    const int quad = lane >> 4;
    const int h    = blockIdx.y;
    const int b    = blockIdx.z;
    // balanced swizzle: co-resident z-parity pairs sum to constant work
    const int qb_i = (b & 1) ? (gridDim.x - 1 - blockIdx.x) : blockIdx.x;
    const int q0   = qb_i * 64;
    const int myq  = q0 + w * 16 + col;

    const ushort* qrow = qkv + (size_t)(b * T + myq) * NTOT + 2 * D + h * D;
    bf16x8 qf[4];
#pragma unroll
    for (int kb2 = 0; kb2 < 4; ++kb2)
        qf[kb2] = *(const bf16x8*)(qrow + kb2 * 32 + quad * 8);

    const ushort* kbase = qkv + (size_t)b * T * NTOT;   // k at col 0
    const ushort* vbase = vbT + (size_t)b * T;          // row stride M_ROWS

    f32x4 O[8];
#pragma unroll
    for (int i = 0; i < 8; ++i) O[i] = (f32x4){0.f, 0.f, 0.f, 0.f};
    float l_r[4] = {0.f, 0.f, 0.f, 0.f};

    const int ntiles = qb_i + 1;
    const int sk_key = lane >> 2;
    const int sk_d   = (lane & 3) * 8;
    const int sv_half = (lane & 1) * 8;

    uint4 kpre[4], vpre[4];
    auto load_tile = [&](int s0) {
#pragma unroll
        for (int kg = 0; kg < 4; ++kg)
            kpre[kg] = *(const uint4*)(kbase + (size_t)(s0 + kg * 16 + sk_key) * NTOT + w * 32 + sk_d);
#pragma unroll
        for (int i2 = 0; i2 < 4; ++i2) {
            const int d = (i2 * 64 + lane) >> 1;
            vpre[i2] = *(const uint4*)(vbase + (size_t)d * M_ROWS + s0 + w * 16 + sv_half);
        }
    };
    auto store_tile = [&]() {
#pragma unroll
        for (int kg = 0; kg < 4; ++kg)
            *(uint4*)(&Ks4[w][kg * 16][0] + (size_t)lane * 8) = kpre[kg];
#pragma unroll
        for (int i2 = 0; i2 < 4; ++i2)
            *(uint4*)(&Vt4[w][i2 * 32][0] + (size_t)lane * 8) = vpre[i2];
    };

    load_tile(0);
    store_tile();
    __syncthreads();

    for (int it = 0; it < ntiles; ++it) {
        const int s0 = it * 64;
        const bool more = (it + 1 < ntiles);
        if (more) load_tile(s0 + 64);      // async; lands during compute below

        // S = Q K^T: 4 subtiles of 16 keys
        f32x4 S[4];
#pragma unroll
        for (int sub = 0; sub < 4; ++sub) {
            f32x4 a = (f32x4){0.f, 0.f, 0.f, 0.f};
#pragma unroll
            for (int kb2 = 0; kb2 < 4; ++kb2) {
                bf16x8 kf = *(const bf16x8*)(&Ks4[kb2][sub * 16 + col][quad * 8]);
                a = __builtin_amdgcn_mfma_f32_16x16x32_bf16(qf[kb2], kf, a, 0, 0, 0);
            }
            S[sub] = a;
        }

        // p = exp(scale*s) with causal mask; per-lane l partials; pack P.
#pragma unroll
        for (int r = 0; r < 4; ++r) {
            const int qq = q0 + w * 16 + quad * 4 + r;
            float p[4];
#pragma unroll
            for (int sub = 0; sub < 4; ++sub) {
                const int key = s0 + sub * 16 + col;
                const float s = (key > qq) ? -1e30f : S[sub][r] * 0.03125f;
                p[sub] = __expf(s);
            }
            l_r[r] += (p[0] + p[1]) + (p[2] + p[3]);
            *(uint32_t*)(&Pt[w][0][quad * 4 + r][col * 2]) =
                f2bf(p[0]) | ((uint32_t)f2bf(p[1]) << 16);
            *(uint32_t*)(&Pt[w][1][quad * 4 + r][col * 2]) =
                f2bf(p[2]) | ((uint32_t)f2bf(p[3]) << 16);
        }

        // O += P V  (P A-layout from per-wave LDS; V B-layout from chunked LDS)
        bf16x8 pa0 = *(const bf16x8*)(&Pt[w][0][col][quad * 8]);
        bf16x8 pa1 = *(const bf16x8*)(&Pt[w][1][col][quad * 8]);
        const int kg0 = quad >> 1;
        const int ko  = (quad & 1) * 8;
#pragma unroll
        for (int nt = 0; nt < 8; ++nt) {
            bf16x8 vf0 = *(const bf16x8*)(&Vt4[kg0][nt * 16 + col][ko]);
            bf16x8 vf1 = *(const bf16x8*)(&Vt4[2 + kg0][nt * 16 + col][ko]);
            O[nt] = __builtin_amdgcn_mfma_f32_16x16x32_bf16(pa0, vf0, O[nt], 0, 0, 0);
            O[nt] = __builtin_amdgcn_mfma_f32_16x16x32_bf16(pa1, vf1, O[nt], 0, 0, 0);
        }

        if (more) {
            __syncthreads();               // all waves done reading K/V LDS
            store_tile();                  // vmcnt wait here is cheap: loads landed
            __syncthreads();               // staged tile visible
        }
    }

    // epilogue: reduce l over the 16-lane col group (once), divide, store bf16
#pragma unroll
    for (int r = 0; r < 4; ++r) {
        float s = l_r[r];
#pragma unroll
        for (int off = 1; off < 16; off <<= 1) s += __shfl_xor(s, off);
        const float inv = 1.0f / s;
        const int t = q0 + w * 16 + quad * 4 + r;
        ushort* orow = attb + (size_t)(b * T + t) * C + h * D;
#pragma unroll
        for (int nt = 0; nt < 8; ++nt) orow[nt * 16 + col] = f2bf(O[nt][r] * inv);
    }
}

// -------------------- Launch --------------------
extern "C" void kernel_launch(void* const* d_in, const int* in_sizes, int n_in,
                              void* d_out, int out_size, void* d_ws, size_t ws_size,
                              hipStream_t stream) {
    const float* x  = (const float*)d_in[0];
    const float* Wk = (const float*)d_in[1];
    const float* Wv = (const float*)d_in[2];
    const float* Wq = (const float*)d_in[3];
    const float* Wp = (const float*)d_in[4];
    const float* bp = (const float*)d_in[5];
    float* out = (float*)d_out;

    char* ws = (char*)d_ws;
    ushort* xb    = (ushort*)ws;                                  // 16 MB (aliased by attb later)
    ushort* attb  = xb;
    ushort* qkv   = (ushort*)(ws + (size_t)16  * 1024 * 1024);    // 20 MB
    ushort* WcatT = (ushort*)(ws + (size_t)36  * 1024 * 1024);    // 2.5 MB
    ushort* WpT   = (ushort*)(ws + (size_t)39  * 1024 * 1024);    // 2 MB
    ushort* vbT   = (ushort*)(ws + (size_t)41  * 1024 * 1024);    // 2 MB

    // 1) conversions (merged weight transpose: one launch)
    xcvt<<<(size_t)M_ROWS * C / (256 * 8), 256, 0, stream>>>(x, xb);
    wtrans_all<<<576, 256, 0, stream>>>(Wk, Wv, Wq, Wp, WcatT, WpT);

    // 2) fused QKV GEMM: [8192,1024] @ [1024,1280] -> qkv bf16
    gemm_mfma<true><<<dim3(NTOT / 128, M_ROWS / 128), 256, 0, stream>>>(
        xb, WcatT, qkv, nullptr, NTOT);

    // 3) v transpose (with key permutation)
    vtrans<<<M_ROWS / 64, 256, 0, stream>>>(qkv, vbT);

    // 4) flash attention (VGPR-prefetch pipeline, balanced swizzle)
    attn_mfma<<<dim3(T / 64, NQ, B), 256, 0, stream>>>(qkv, vbT, attb);

    // 5) projection: [8192,1024] @ [1024,1024] + bp -> out f32
    gemm_mfma<false><<<dim3(C / 128, M_ROWS / 128), 256, 0, stream>>>(
        attb, WpT, out, bp, C);
}

// Round 11
// 251.678 us; speedup vs baseline: 1.5475x; 1.5475x over previous
//
#include <hip/hip_runtime.h>
#include <hip/hip_bf16.h>
#include <cstddef>
#include <cstdint>

// Problem constants
#define B 4
#define T 2048
#define C 1024
#define NQ 8
#define D 128
#define M_ROWS (B * T)          // 8192
#define NTOT (2 * D + NQ * D)   // 1280: [k | v | q0..q7]

typedef __bf16 bf16x8 __attribute__((ext_vector_type(8)));
typedef float  f32x4  __attribute__((ext_vector_type(4)));

__device__ __forceinline__ ushort f2bf(float f) {
    union { float f; uint32_t u; } v; v.f = f;
    const uint32_t r = (v.u + 0x7fffu + ((v.u >> 16) & 1u)) >> 16;
    return (ushort)r;
}

__device__ __forceinline__ void gld_lds16(const ushort* g, ushort* lds_uniform) {
    __builtin_amdgcn_global_load_lds(
        (const __attribute__((address_space(1))) void*)g,
        (__attribute__((address_space(3))) void*)lds_uniform, 16, 0, 0);
}

// -------------------- weight transpose+convert: src f32 [1024][NC] -> dst bf16 [NC][1024]
__device__ __forceinline__ void wtrans_body(const float* __restrict__ src,
                                            ushort* __restrict__ dst, int NC,
                                            int bx, int by) {
    __shared__ ushort Ts[64][72];
    const int tid = threadIdx.x;
    const int k0 = by * 64, c0 = bx * 64;
    {
        const int r = tid >> 2, cq = tid & 3;
#pragma unroll
        for (int i = 0; i < 4; ++i) {
            const int cc = cq * 16 + i * 4;
            const float4 v = *(const float4*)(src + (size_t)(k0 + r) * NC + c0 + cc);
            uint2 o;
            o.x = f2bf(v.x) | ((uint32_t)f2bf(v.y) << 16);
            o.y = f2bf(v.z) | ((uint32_t)f2bf(v.w) << 16);
            *(uint2*)(&Ts[r][cc]) = o;
        }
    }
    __syncthreads();
    {
        const int n = tid >> 2, kq = tid & 3;
        ushort vv[16];
#pragma unroll
        for (int j = 0; j < 16; ++j) vv[j] = Ts[kq * 16 + j][n];
        uint4 o0, o1;
        o0.x = vv[0] | ((uint32_t)vv[1] << 16);  o0.y = vv[2] | ((uint32_t)vv[3] << 16);
        o0.z = vv[4] | ((uint32_t)vv[5] << 16);  o0.w = vv[6] | ((uint32_t)vv[7] << 16);
        o1.x = vv[8] | ((uint32_t)vv[9] << 16);  o1.y = vv[10] | ((uint32_t)vv[11] << 16);
        o1.z = vv[12] | ((uint32_t)vv[13] << 16); o1.w = vv[14] | ((uint32_t)vv[15] << 16);
        ushort* d = dst + (size_t)(c0 + n) * C + k0 + kq * 16;
        *(uint4*)d = o0;
        *(uint4*)(d + 8) = o1;
    }
}

// merged weight transpose: flat grid of 576 blocks.
__global__ __launch_bounds__(256) void wtrans_all(const float* __restrict__ Wk,
                                                  const float* __restrict__ Wv,
                                                  const float* __restrict__ Wq,
                                                  const float* __restrict__ Wp,
                                                  ushort* __restrict__ WcatT,
                                                  ushort* __restrict__ WpT) {
    const int id = blockIdx.x;
    if (id < 320) {
        const int z = id >> 5, rem = id & 31;
        const float* src;
        int rbase;
        if (z == 0)      { src = Wk; rbase = 0; }
        else if (z == 1) { src = Wv; rbase = D; }
        else             { src = Wq + (size_t)(z - 2) * C * D; rbase = 2 * D + (z - 2) * D; }
        wtrans_body(src, WcatT + (size_t)rbase * C, D, rem & 1, rem >> 1);
    } else {
        const int id2 = id - 320;
        wtrans_body(Wp, WpT, C, id2 & 15, id2 >> 4);
    }
}

// -------------------- v transpose with per-32-key interleave permutation -----
// vb rows are qkv[row][D..2D); out vbT[d][g*32 + pi(k)], pi(k) = (k&15)*2 + (k>>4)
__global__ __launch_bounds__(256) void vtrans(const ushort* __restrict__ qkv,
                                              ushort* __restrict__ vbT) {
    __shared__ ushort Ts[64][136];
    const int tid = threadIdx.x;
    const int kb0 = blockIdx.x * 64;
    {
        const int r = tid >> 2, cq = tid & 3;
        const ushort* src = qkv + (size_t)(kb0 + r) * NTOT + D;
#pragma unroll
        for (int i = 0; i < 4; ++i) {
            const int cc = (cq * 4 + i) * 8;
            *(uint4*)(&Ts[r][cc]) = *(const uint4*)(src + cc);
        }
    }
    __syncthreads();
    {
        const int d = tid >> 1, half = tid & 1;
        ushort vv[32];
#pragma unroll
        for (int k = 0; k < 32; ++k) vv[k] = Ts[half * 32 + k][d];
        uint32_t dw[16];
#pragma unroll
        for (int i = 0; i < 16; ++i) dw[i] = vv[i] | ((uint32_t)vv[16 + i] << 16);
        uint32_t* dst = (uint32_t*)(vbT + (size_t)d * M_ROWS + kb0 + half * 32);
#pragma unroll
        for (int i = 0; i < 4; ++i)
            *(uint4*)(dst + i * 4) = *(uint4*)(&dw[i * 4]);
    }
}

// -------------------- MFMA GEMM -----------------------------------------
// A: [M][1024] (f32 if CVT_A, converted in-flight during staging; else bf16)
// Bt: [N][1024] bf16. 128x128 tile, BK=32, 4 waves x 4x4 16x16x32 MFMAs.
template <bool BF16_OUT, bool CVT_A>
__global__ __launch_bounds__(256) void gemm_mfma(const float* __restrict__ Af,
                                                 const ushort* __restrict__ Ab,
                                                 const ushort* __restrict__ Bt,
                                                 void* __restrict__ Cout,
                                                 const float* __restrict__ bias,
                                                 const int Nout) {
    __shared__ ushort As[128 * 32];
    __shared__ ushort Bs[128 * 32];
    const int tid  = threadIdx.x;
    const int lane = tid & 63;
    const int w    = tid >> 6;
    const int col  = lane & 15;
    const int quad = lane >> 4;
    const int row0 = blockIdx.y * 128;
    const int col0 = blockIdx.x * 128;
    const int wm = w & 1, wn = w >> 1;

    const int srow = lane >> 2;
    const int skk  = (lane & 3) * 8;

    f32x4 acc[4][4];
#pragma unroll
    for (int i = 0; i < 4; ++i)
#pragma unroll
        for (int j = 0; j < 4; ++j) acc[i][j] = (f32x4){0.f, 0.f, 0.f, 0.f};

    for (int k0 = 0; k0 < C; k0 += 32) {
        __syncthreads();
#pragma unroll
        for (int j = 0; j < 2; ++j) {
            const int ci = w * 2 + j;
            const int r  = ci * 16 + srow;
            if (CVT_A) {
                // in-flight f32 -> bf16: same LDS placement as gld_lds (lane*16B)
                const float* src = Af + (size_t)(row0 + r) * C + k0 + skk;
                const float4 a0 = *(const float4*)src;
                const float4 a1 = *(const float4*)(src + 4);
                uint4 o;
                o.x = f2bf(a0.x) | ((uint32_t)f2bf(a0.y) << 16);
                o.y = f2bf(a0.z) | ((uint32_t)f2bf(a0.w) << 16);
                o.z = f2bf(a1.x) | ((uint32_t)f2bf(a1.y) << 16);
                o.w = f2bf(a1.z) | ((uint32_t)f2bf(a1.w) << 16);
                *(uint4*)(&As[ci * 512] + (size_t)lane * 8) = o;
            } else {
                gld_lds16(Ab + (size_t)(row0 + r) * C + k0 + skk, &As[ci * 512]);
            }
            gld_lds16(Bt + (size_t)(col0 + r) * C + k0 + skk, &Bs[ci * 512]);
        }
        __syncthreads();

        bf16x8 af[4], bfr[4];
#pragma unroll
        for (int i = 0; i < 4; ++i)
            af[i] = *(const bf16x8*)&As[(wm * 64 + i * 16 + col) * 32 + quad * 8];
#pragma unroll
        for (int j = 0; j < 4; ++j)
            bfr[j] = *(const bf16x8*)&Bs[(wn * 64 + j * 16 + col) * 32 + quad * 8];
#pragma unroll
        for (int i = 0; i < 4; ++i)
#pragma unroll
            for (int j = 0; j < 4; ++j)
                acc[i][j] = __builtin_amdgcn_mfma_f32_16x16x32_bf16(af[i], bfr[j], acc[i][j], 0, 0, 0);
    }

#pragma unroll
    for (int i = 0; i < 4; ++i) {
#pragma unroll
        for (int r = 0; r < 4; ++r) {
            const int grow = row0 + wm * 64 + i * 16 + quad * 4 + r;
#pragma unroll
            for (int j = 0; j < 4; ++j) {
                const int gcol = col0 + wn * 64 + j * 16 + col;
                const float v = acc[i][j][r];
                if (BF16_OUT) {
                    ((ushort*)Cout)[(size_t)grow * Nout + gcol] = f2bf(v);
                } else {
                    ((float*)Cout)[(size_t)grow * Nout + gcol] = v + bias[gcol];
                }
            }
        }
    }
}

// -------------------- MFMA flash attention (R8 exact) --------------------
// 64-query blocks, 4 waves, 64-key tiles, no-max exact softmax, gld_lds
// staging, balanced parity swizzle (co-resident z-parity pairs sum to
// constant work -> equal per-CU load).
__global__ __launch_bounds__(256) void attn_mfma(const ushort* __restrict__ qkv,
                                                 const ushort* __restrict__ vbT,
                                                 ushort* __restrict__ attb) {
    __shared__ ushort Ks4[4][64][32];    // [d-chunk][key][32 d]  16 KB
    __shared__ ushort Vt4[4][128][16];   // [key-chunk][d][16 keys] 16 KB
    __shared__ ushort Pt[4][2][16][32];  // [wave][key-group][q-row][32 pkeys] 8 KB

    const int tid  = threadIdx.x;
    const int lane = tid & 63;
    const int w    = tid >> 6;
    const int col  = lane & 15;
    const int quad = lane >> 4;
    const int h    = blockIdx.y;
    const int b    = blockIdx.z;
    const int qb_i = (b & 1) ? (gridDim.x - 1 - blockIdx.x) : blockIdx.x;
    const int q0   = qb_i * 64;
    const int myq  = q0 + w * 16 + col;

    const ushort* qrow = qkv + (size_t)(b * T + myq) * NTOT + 2 * D + h * D;
    bf16x8 qf[4];
#pragma unroll
    for (int kb2 = 0; kb2 < 4; ++kb2)
        qf[kb2] = *(const bf16x8*)(qrow + kb2 * 32 + quad * 8);

    const ushort* kbase = qkv + (size_t)b * T * NTOT;   // k at col 0
    const ushort* vbase = vbT + (size_t)b * T;          // row stride M_ROWS

    f32x4 O[8];
#pragma unroll
    for (int i = 0; i < 8; ++i) O[i] = (f32x4){0.f, 0.f, 0.f, 0.f};
    float l_r[4] = {0.f, 0.f, 0.f, 0.f};

    const int ntiles = qb_i + 1;
    const int sk_key = lane >> 2;
    const int sk_d   = (lane & 3) * 8;
    const int sv_half = (lane & 1) * 8;

    for (int it = 0; it < ntiles; ++it) {
        const int s0 = it * 64;
        __syncthreads();
#pragma unroll
        for (int kg = 0; kg < 4; ++kg) {
            gld_lds16(kbase + (size_t)(s0 + kg * 16 + sk_key) * NTOT + w * 32 + sk_d,
                      &Ks4[w][kg * 16][0]);
        }
#pragma unroll
        for (int i2 = 0; i2 < 4; ++i2) {
            const int d = (i2 * 64 + lane) >> 1;
            gld_lds16(vbase + (size_t)d * M_ROWS + s0 + w * 16 + sv_half,
                      &Vt4[w][i2 * 32][0]);
        }
        __syncthreads();

        // S = Q K^T: 4 subtiles of 16 keys
        f32x4 S[4];
#pragma unroll
        for (int sub = 0; sub < 4; ++sub) {
            f32x4 a = (f32x4){0.f, 0.f, 0.f, 0.f};
#pragma unroll
            for (int kb2 = 0; kb2 < 4; ++kb2) {
                bf16x8 kf = *(const bf16x8*)(&Ks4[kb2][sub * 16 + col][quad * 8]);
                a = __builtin_amdgcn_mfma_f32_16x16x32_bf16(qf[kb2], kf, a, 0, 0, 0);
            }
            S[sub] = a;
        }

        // p = exp(scale*s) with causal mask; per-lane l partials; pack P.
#pragma unroll
        for (int r = 0; r < 4; ++r) {
            const int qq = q0 + w * 16 + quad * 4 + r;
            float p[4];
#pragma unroll
            for (int sub = 0; sub < 4; ++sub) {
                const int key = s0 + sub * 16 + col;
                const float s = (key > qq) ? -1e30f : S[sub][r] * 0.03125f;
                p[sub] = __expf(s);
            }
            l_r[r] += (p[0] + p[1]) + (p[2] + p[3]);
            *(uint32_t*)(&Pt[w][0][quad * 4 + r][col * 2]) =
                f2bf(p[0]) | ((uint32_t)f2bf(p[1]) << 16);
            *(uint32_t*)(&Pt[w][1][quad * 4 + r][col * 2]) =
                f2bf(p[2]) | ((uint32_t)f2bf(p[3]) << 16);
        }

        // O += P V  (P A-layout from per-wave LDS; V B-layout from chunked LDS)
        bf16x8 pa0 = *(const bf16x8*)(&Pt[w][0][col][quad * 8]);
        bf16x8 pa1 = *(const bf16x8*)(&Pt[w][1][col][quad * 8]);
        const int kg0 = quad >> 1;
        const int ko  = (quad & 1) * 8;
#pragma unroll
        for (int nt = 0; nt < 8; ++nt) {
            bf16x8 vf0 = *(const bf16x8*)(&Vt4[kg0][nt * 16 + col][ko]);
            bf16x8 vf1 = *(const bf16x8*)(&Vt4[2 + kg0][nt * 16 + col][ko]);
            O[nt] = __builtin_amdgcn_mfma_f32_16x16x32_bf16(pa0, vf0, O[nt], 0, 0, 0);
            O[nt] = __builtin_amdgcn_mfma_f32_16x16x32_bf16(pa1, vf1, O[nt], 0, 0, 0);
        }
    }

    // epilogue: reduce l over the 16-lane col group (once), divide, store bf16
#pragma unroll
    for (int r = 0; r < 4; ++r) {
        float s = l_r[r];
#pragma unroll
        for (int off = 1; off < 16; off <<= 1) s += __shfl_xor(s, off);
        const float inv = 1.0f / s;
        const int t = q0 + w * 16 + quad * 4 + r;
        ushort* orow = attb + (size_t)(b * T + t) * C + h * D;
#pragma unroll
        for (int nt = 0; nt < 8; ++nt) orow[nt * 16 + col] = f2bf(O[nt][r] * inv);
    }
}

// -------------------- Launch --------------------
extern "C" void kernel_launch(void* const* d_in, const int* in_sizes, int n_in,
                              void* d_out, int out_size, void* d_ws, size_t ws_size,
                              hipStream_t stream) {
    const float* x  = (const float*)d_in[0];
    const float* Wk = (const float*)d_in[1];
    const float* Wv = (const float*)d_in[2];
    const float* Wq = (const float*)d_in[3];
    const float* Wp = (const float*)d_in[4];
    const float* bp = (const float*)d_in[5];
    float* out = (float*)d_out;

    char* ws = (char*)d_ws;
    ushort* attb  = (ushort*)ws;                                  // 16 MB
    ushort* qkv   = (ushort*)(ws + (size_t)16  * 1024 * 1024);    // 20 MB
    ushort* WcatT = (ushort*)(ws + (size_t)36  * 1024 * 1024);    // 2.5 MB
    ushort* WpT   = (ushort*)(ws + (size_t)39  * 1024 * 1024);    // 2 MB
    ushort* vbT   = (ushort*)(ws + (size_t)41  * 1024 * 1024);    // 2 MB

    // 1) weight transpose+convert (one launch)
    wtrans_all<<<576, 256, 0, stream>>>(Wk, Wv, Wq, Wp, WcatT, WpT);

    // 2) fused QKV GEMM with in-flight x f32->bf16: [8192,1024] @ [1024,1280]
    gemm_mfma<true, true><<<dim3(NTOT / 128, M_ROWS / 128), 256, 0, stream>>>(
        x, nullptr, WcatT, qkv, nullptr, NTOT);

    // 3) v transpose (with key permutation)
    vtrans<<<M_ROWS / 64, 256, 0, stream>>>(qkv, vbT);

    // 4) flash attention (R8 exact)
    attn_mfma<<<dim3(T / 64, NQ, B), 256, 0, stream>>>(qkv, vbT, attb);

    // 5) projection: [8192,1024] @ [1024,1024] + bp -> out f32
    gemm_mfma<false, false><<<dim3(C / 128, M_ROWS / 128), 256, 0, stream>>>(
        nullptr, attb, WpT, out, bp, C);
}